// Round 1
// baseline (353.253 us; speedup 1.0000x reference)
//
#include <hip/hip_runtime.h>

#define ISZ 128
#define HW (ISZ * ISZ)
#define TSZ 4
#define NEARP 0.1f
#define FARP 100.0f
#define EPSF 1e-9f
#define REC 20   // floats per face record

// Record layout (floats):
// 0..3  : umin, umax, vmin, vmax   (bbox, disabled => +/-1e30 when det clamped)
// 4..12 : coef c00..c22 (row-major)
// 13..15: z0, z1, z2 (camera z per vertex)
// 16    : light scalar
// 17..19: pad

__global__ void face_pre(const float* __restrict__ T,
                         const float* __restrict__ verts,
                         const int* __restrict__ faces,
                         const float* __restrict__ Km,
                         const float* __restrict__ dist,
                         float* __restrict__ rec,
                         int B, int V, int F) {
#pragma clang fp contract(off)
    int t = blockIdx.x * blockDim.x + threadIdx.x;
    if (t >= B * F) return;
    int b = t / F, f = t - b * F;

    const float* Tb = T + b * 16;
    const float* Kb = Km + b * 9;
    const float* Db = dist + b * 5;
    float k1 = Db[0], k2 = Db[1], p1 = Db[2], p2 = Db[3], k3 = Db[4];

    int idx0 = faces[((size_t)b * F + f) * 3 + 0];
    int idx1 = faces[((size_t)b * F + f) * 3 + 1];
    int idx2 = faces[((size_t)b * F + f) * 3 + 2];
    int idx[3] = {idx0, idx1, idx2};

    float P[3][3];
    for (int k = 0; k < 3; ++k) {
        const float* vp = verts + ((size_t)b * V + idx[k]) * 3;
        P[k][0] = vp[0]; P[k][1] = vp[1]; P[k][2] = vp[2];
    }

    // ---- lighting: n = cross(v12, v10), normalized; cos = relu(n_y) ----
    float v10x = P[0][0] - P[1][0], v10y = P[0][1] - P[1][1], v10z = P[0][2] - P[1][2];
    float v12x = P[2][0] - P[1][0], v12y = P[2][1] - P[1][1], v12z = P[2][2] - P[1][2];
    float nx = v12y * v10z - v12z * v10y;
    float ny = v12z * v10x - v12x * v10z;
    float nz = v12x * v10y - v12y * v10x;
    float norm = sqrtf((nx * nx + ny * ny) + nz * nz);
    float cosv = ny / (norm + EPSF);
    cosv = fmaxf(cosv, 0.0f);
    float light = 0.5f + 0.5f * cosv;

    // ---- project the 3 vertices (exact reference op order) ----
    float xs[3], ys[3], zs[3];
    for (int k = 0; k < 3; ++k) {
        float X = P[k][0], Y = P[k][1], Z = P[k][2];
        float vcx = ((Tb[0] * X + Tb[1] * Y) + Tb[2] * Z) + Tb[3];
        float vcy = ((Tb[4] * X + Tb[5] * Y) + Tb[6] * Z) + Tb[7];
        float vcz = ((Tb[8] * X + Tb[9] * Y) + Tb[10] * Z) + Tb[11];
        float zq = vcz + EPSF;
        float x_ = vcx / zq;
        float y_ = vcy / zq;
        float r2 = x_ * x_ + y_ * y_;
        float rad = ((1.0f + k1 * r2) + (k2 * r2) * r2) + ((k3 * r2) * r2) * r2;
        float xd = (x_ * rad + ((2.0f * p1) * x_) * y_) + p2 * (r2 + (2.0f * x_) * x_);
        float yd = (y_ * rad + p1 * (r2 + (2.0f * y_) * y_)) + ((2.0f * p2) * x_) * y_;
        float pixx = (Kb[0] * xd + Kb[1] * yd) + Kb[2];
        float pixy = (Kb[3] * xd + Kb[4] * yd) + Kb[5];
        float u = (2.0f * (pixx - (float)ISZ / 2.0f)) / (float)ISZ;
        float v = (2.0f * (((float)ISZ - pixy) - (float)ISZ / 2.0f)) / (float)ISZ;
        xs[k] = u; ys[k] = v; zs[k] = vcz;
    }

    float x0 = xs[0], x1 = xs[1], x2 = xs[2];
    float y0 = ys[0], y1 = ys[1], y2 = ys[2];

    float det = (x0 * (y1 - y2) + x1 * (y2 - y0)) + x2 * (y0 - y1);
    bool degen = fabsf(det) < 1e-6f;
    if (degen) det = 1e-6f;

    float c00 = (y1 - y2) / det, c01 = (x2 - x1) / det, c02 = (x1 * y2 - x2 * y1) / det;
    float c10 = (y2 - y0) / det, c11 = (x0 - x2) / det, c12 = (x2 * y0 - x0 * y2) / det;
    float c20 = (y0 - y1) / det, c21 = (x1 - x0) / det, c22 = (x0 * y1 - x1 * y0) / det;

    float umin, umax, vmin, vmax;
    if (degen) {
        // clamped det => "inside" region is a thin band along an infinite line;
        // cannot bbox-cull without risking mismatch vs reference.
        umin = -1e30f; umax = 1e30f; vmin = -1e30f; vmax = 1e30f;
    } else {
        umin = fminf(fminf(x0, x1), x2) - 1e-3f;
        umax = fmaxf(fmaxf(x0, x1), x2) + 1e-3f;
        vmin = fminf(fminf(y0, y1), y2) - 1e-3f;
        vmax = fmaxf(fmaxf(y0, y1), y2) + 1e-3f;
    }

    float* r = rec + (size_t)t * REC;
    r[0] = umin; r[1] = umax; r[2] = vmin; r[3] = vmax;
    r[4] = c00; r[5] = c01; r[6] = c02;
    r[7] = c10; r[8] = c11; r[9] = c12;
    r[10] = c20; r[11] = c21; r[12] = c22;
    r[13] = zs[0]; r[14] = zs[1]; r[15] = zs[2];
    r[16] = light;
    r[17] = 0.0f; r[18] = 0.0f; r[19] = 0.0f;
}

__global__ __launch_bounds__(64) void raster(const float* __restrict__ rec,
                                             const float* __restrict__ tex,
                                             float* __restrict__ out,
                                             int B, int F) {
#pragma clang fp contract(off)
    int t = blockIdx.x * blockDim.x + threadIdx.x;
    if (t >= B * HW) return;
    int b = t / HW, p = t - b * HW;
    int i = p / ISZ, j = p - i * ISZ;
    float px = (float)(2 * j + 1 - ISZ) / (float)ISZ;
    float py = (float)(2 * i + 1 - ISZ) / (float)ISZ;

    float best = FARP;
    int bestf = -1;
    float bw0 = 0, bw1 = 0, bw2 = 0, bz0 = 1, bz1 = 1, bz2 = 1, blight = 0;

    const float* rb = rec + (size_t)b * F * REC;
    for (int f = 0; f < F; ++f) {
        const float* r = rb + (size_t)f * REC;
        float umin = r[0], umax = r[1], vmin = r[2], vmax = r[3];
        if (px < umin || px > umax || py < vmin || py > vmax) continue;

        float w0 = (r[4] * px + r[5] * py) + r[6];
        float w1 = (r[7] * px + r[8] * py) + r[9];
        float w2 = (r[10] * px + r[11] * py) + r[12];
        bool inside = (w0 >= 0.0f) & (w0 <= 1.0f) &
                      (w1 >= 0.0f) & (w1 <= 1.0f) &
                      (w2 >= 0.0f) & (w2 <= 1.0f);
        if (!inside) continue;

        float z0 = r[13], z1 = r[14], z2 = r[15];
        float s = ((w0 / z0) + (w1 / z1)) + (w2 / z2);
        float zp = 1.0f / s;
        if (zp > NEARP && zp < FARP && zp < best) {
            best = zp; bestf = f;
            bw0 = w0; bw1 = w1; bw2 = w2;
            bz0 = z0; bz1 = z1; bz2 = z2;
            blight = r[16];
        }
    }

    float o0 = 0.0f, o1 = 0.0f, o2 = 0.0f;
    if (bestf >= 0) {
        float wp0 = (bw0 / bz0) * best;
        float wp1 = (bw1 / bz1) * best;
        float wp2 = (bw2 / bz2) * best;
        wp0 = fminf(fmaxf(wp0, 0.0f), 1.0f);
        wp1 = fminf(fmaxf(wp1, 0.0f), 1.0f);
        wp2 = fminf(fmaxf(wp2, 0.0f), 1.0f);
        float ssum = ((wp0 + wp1) + wp2) + EPSF;
        wp0 = wp0 / ssum; wp1 = wp1 / ssum; wp2 = wp2 / ssum;
        int t0 = min(max((int)floorf(wp0 * (float)TSZ), 0), TSZ - 1);
        int t1 = min(max((int)floorf(wp1 * (float)TSZ), 0), TSZ - 1);
        int t2 = min(max((int)floorf(wp2 * (float)TSZ), 0), TSZ - 1);
        const float* tp = tex + ((((((size_t)b * F + bestf) * TSZ + t0) * TSZ + t1) * TSZ + t2) * 3);
        o0 = tp[0] * blight;
        o1 = tp[1] * blight;
        o2 = tp[2] * blight;
    }

    out[((size_t)b * 3 + 0) * HW + p] = o0;
    out[((size_t)b * 3 + 1) * HW + p] = o1;
    out[((size_t)b * 3 + 2) * HW + p] = o2;
}

extern "C" void kernel_launch(void* const* d_in, const int* in_sizes, int n_in,
                              void* d_out, int out_size, void* d_ws, size_t ws_size,
                              hipStream_t stream) {
    const float* T     = (const float*)d_in[0];
    const float* verts = (const float*)d_in[1];
    const int*   faces = (const int*)d_in[2];
    const float* tex   = (const float*)d_in[3];
    const float* Km    = (const float*)d_in[4];
    const float* dist  = (const float*)d_in[5];

    int B = in_sizes[0] / 16;
    int V = in_sizes[1] / (3 * B);
    int F = in_sizes[2] / (3 * B);

    float* rec = (float*)d_ws;  // B*F*REC floats = 160 KB for B=2,F=1000

    int nfaces = B * F;
    face_pre<<<(nfaces + 255) / 256, 256, 0, stream>>>(T, verts, faces, Km, dist, rec, B, V, F);

    int npix = B * HW;
    raster<<<(npix + 63) / 64, 64, 0, stream>>>(rec, tex, (float*)d_out, B, F);
}

// Round 4
// 166.626 us; speedup vs baseline: 2.1200x; 2.1200x over previous
//
#include <hip/hip_runtime.h>

#define ISZ 128
#define HW (ISZ * ISZ)
#define TSZ 4
#define NEARP 0.1f
#define FARP 100.0f
#define EPSF 1e-9f
#define REC 20   // floats per face record (80B, float4-aligned)
#define TILE 8
#define NTJ (ISZ / TILE)     // 16 tiles per row
#define NTILES (NTJ * NTJ)   // 256 tiles per image

// Record layout (floats):
// 0..3  : umin, umax, vmin, vmax   (bbox, disabled => +/-1e30 when det clamped)
// 4..12 : coef c00..c22 (row-major)
// 13..15: z0, z1, z2 (camera z per vertex)
// 16    : light scalar
// 17..19: pad

__global__ void face_pre(const float* __restrict__ T,
                         const float* __restrict__ verts,
                         const int* __restrict__ faces,
                         const float* __restrict__ Km,
                         const float* __restrict__ dist,
                         float* __restrict__ rec,
                         int B, int V, int F) {
#pragma clang fp contract(off)
    int t = blockIdx.x * blockDim.x + threadIdx.x;
    if (t >= B * F) return;
    int b = t / F, f = t - b * F;

    const float* Tb = T + b * 16;
    const float* Kb = Km + b * 9;
    const float* Db = dist + b * 5;
    float k1 = Db[0], k2 = Db[1], p1 = Db[2], p2 = Db[3], k3 = Db[4];

    int idx0 = faces[((size_t)b * F + f) * 3 + 0];
    int idx1 = faces[((size_t)b * F + f) * 3 + 1];
    int idx2 = faces[((size_t)b * F + f) * 3 + 2];
    int idx[3] = {idx0, idx1, idx2};

    float P[3][3];
    for (int k = 0; k < 3; ++k) {
        const float* vp = verts + ((size_t)b * V + idx[k]) * 3;
        P[k][0] = vp[0]; P[k][1] = vp[1]; P[k][2] = vp[2];
    }

    // ---- lighting: n = cross(v12, v10), normalized; cos = relu(n_y) ----
    float v10x = P[0][0] - P[1][0], v10y = P[0][1] - P[1][1], v10z = P[0][2] - P[1][2];
    float v12x = P[2][0] - P[1][0], v12y = P[2][1] - P[1][1], v12z = P[2][2] - P[1][2];
    float nx = v12y * v10z - v12z * v10y;
    float ny = v12z * v10x - v12x * v10z;
    float nz = v12x * v10y - v12y * v10x;
    float norm = sqrtf((nx * nx + ny * ny) + nz * nz);
    float cosv = ny / (norm + EPSF);
    cosv = fmaxf(cosv, 0.0f);
    float light = 0.5f + 0.5f * cosv;

    // ---- project the 3 vertices (exact reference op order) ----
    float xs[3], ys[3], zs[3];
    for (int k = 0; k < 3; ++k) {
        float X = P[k][0], Y = P[k][1], Z = P[k][2];
        float vcx = ((Tb[0] * X + Tb[1] * Y) + Tb[2] * Z) + Tb[3];
        float vcy = ((Tb[4] * X + Tb[5] * Y) + Tb[6] * Z) + Tb[7];
        float vcz = ((Tb[8] * X + Tb[9] * Y) + Tb[10] * Z) + Tb[11];
        float zq = vcz + EPSF;
        float x_ = vcx / zq;
        float y_ = vcy / zq;
        float r2 = x_ * x_ + y_ * y_;
        float rad = ((1.0f + k1 * r2) + (k2 * r2) * r2) + ((k3 * r2) * r2) * r2;
        float xd = (x_ * rad + ((2.0f * p1) * x_) * y_) + p2 * (r2 + (2.0f * x_) * x_);
        float yd = (y_ * rad + p1 * (r2 + (2.0f * y_) * y_)) + ((2.0f * p2) * x_) * y_;
        float pixx = (Kb[0] * xd + Kb[1] * yd) + Kb[2];
        float pixy = (Kb[3] * xd + Kb[4] * yd) + Kb[5];
        float u = (2.0f * (pixx - (float)ISZ / 2.0f)) / (float)ISZ;
        float v = (2.0f * (((float)ISZ - pixy) - (float)ISZ / 2.0f)) / (float)ISZ;
        xs[k] = u; ys[k] = v; zs[k] = vcz;
    }

    float x0 = xs[0], x1 = xs[1], x2 = xs[2];
    float y0 = ys[0], y1 = ys[1], y2 = ys[2];

    float det = (x0 * (y1 - y2) + x1 * (y2 - y0)) + x2 * (y0 - y1);
    bool degen = fabsf(det) < 1e-6f;
    if (degen) det = 1e-6f;

    float c00 = (y1 - y2) / det, c01 = (x2 - x1) / det, c02 = (x1 * y2 - x2 * y1) / det;
    float c10 = (y2 - y0) / det, c11 = (x0 - x2) / det, c12 = (x2 * y0 - x0 * y2) / det;
    float c20 = (y0 - y1) / det, c21 = (x1 - x0) / det, c22 = (x0 * y1 - x1 * y0) / det;

    float umin, umax, vmin, vmax;
    if (degen) {
        // clamped det => "inside" region is a thin band along an infinite line;
        // cannot bbox-cull without risking mismatch vs reference.
        umin = -1e30f; umax = 1e30f; vmin = -1e30f; vmax = 1e30f;
    } else {
        umin = fminf(fminf(x0, x1), x2) - 1e-3f;
        umax = fmaxf(fmaxf(x0, x1), x2) + 1e-3f;
        vmin = fminf(fminf(y0, y1), y2) - 1e-3f;
        vmax = fmaxf(fmaxf(y0, y1), y2) + 1e-3f;
    }

    float* r = rec + (size_t)t * REC;
    r[0] = umin; r[1] = umax; r[2] = vmin; r[3] = vmax;
    r[4] = c00; r[5] = c01; r[6] = c02;
    r[7] = c10; r[8] = c11; r[9] = c12;
    r[10] = c20; r[11] = c21; r[12] = c22;
    r[13] = zs[0]; r[14] = zs[1]; r[15] = zs[2];
    r[16] = light;
    r[17] = 0.0f; r[18] = 0.0f; r[19] = 0.0f;
}

// One wave (64 threads) per 8x8 pixel tile. Faces staged chunk-wise:
// each lane bbox-tests one face vs the tile rect, ballot+popcount compacts
// passing faces IN FACE ORDER (preserves argmin first-occurrence tie-break)
// into LDS; then all 64 pixels scan the candidates from LDS (broadcast reads).
__global__ __launch_bounds__(64) void raster_tiled(const float* __restrict__ rec,
                                                   const float* __restrict__ tex,
                                                   float* __restrict__ out,
                                                   int B, int F) {
#pragma clang fp contract(off)
    __shared__ float cand[64][14];  // c00..c22, z0,z1,z2, light, faceidx(bits)

    int blk = blockIdx.x;
    int b = blk / NTILES, tile = blk - b * NTILES;
    int ti = tile / NTJ, tj = tile - ti * NTJ;
    int lane = threadIdx.x;
    int li = lane / TILE, lj = lane - li * TILE;
    int i = ti * TILE + li;
    int j = tj * TILE + lj;

    float px = (float)(2 * j + 1 - ISZ) / (float)ISZ;
    float py = (float)(2 * i + 1 - ISZ) / (float)ISZ;
    float pxmin = (float)(2 * (tj * TILE) + 1 - ISZ) / (float)ISZ;
    float pxmax = (float)(2 * (tj * TILE + TILE - 1) + 1 - ISZ) / (float)ISZ;
    float pymin = (float)(2 * (ti * TILE) + 1 - ISZ) / (float)ISZ;
    float pymax = (float)(2 * (ti * TILE + TILE - 1) + 1 - ISZ) / (float)ISZ;

    const float* rb = rec + (size_t)b * F * REC;

    float best = FARP;
    int bestf = -1;
    float bw0 = 0, bw1 = 0, bw2 = 0, bz0 = 1, bz1 = 1, bz2 = 1, blight = 0;

    for (int c0 = 0; c0 < F; c0 += 64) {
        int f = c0 + lane;
        const float* r = rb + (size_t)f * REC;
        bool pass = false;
        if (f < F) {
            float4 bb = *(const float4*)r;  // umin,umax,vmin,vmax
            pass = (bb.x <= pxmax) & (bb.y >= pxmin) & (bb.z <= pymax) & (bb.w >= pymin);
        }
        unsigned long long m = __ballot(pass);
        int nc = __popcll(m);
        if (pass) {
            int slot = __popcll(m & ((1ull << lane) - 1ull));
            #pragma unroll
            for (int q = 0; q < 13; ++q) cand[slot][q] = r[4 + q];
            cand[slot][13] = __int_as_float(f);
        }
        __syncthreads();

        for (int k = 0; k < nc; ++k) {
            float w0 = (cand[k][0] * px + cand[k][1] * py) + cand[k][2];
            float w1 = (cand[k][3] * px + cand[k][4] * py) + cand[k][5];
            float w2 = (cand[k][6] * px + cand[k][7] * py) + cand[k][8];
            bool inside = (w0 >= 0.0f) & (w0 <= 1.0f) &
                          (w1 >= 0.0f) & (w1 <= 1.0f) &
                          (w2 >= 0.0f) & (w2 <= 1.0f);
            if (!inside) continue;
            float z0 = cand[k][9], z1 = cand[k][10], z2 = cand[k][11];
            float s = ((w0 / z0) + (w1 / z1)) + (w2 / z2);
            float zp = 1.0f / s;
            if (zp > NEARP && zp < FARP && zp < best) {
                best = zp; bestf = __float_as_int(cand[k][13]);
                bw0 = w0; bw1 = w1; bw2 = w2;
                bz0 = z0; bz1 = z1; bz2 = z2;
                blight = cand[k][12];
            }
        }
        __syncthreads();
    }

    float o0 = 0.0f, o1 = 0.0f, o2 = 0.0f;
    if (bestf >= 0) {
        float wp0 = (bw0 / bz0) * best;
        float wp1 = (bw1 / bz1) * best;
        float wp2 = (bw2 / bz2) * best;
        wp0 = fminf(fmaxf(wp0, 0.0f), 1.0f);
        wp1 = fminf(fmaxf(wp1, 0.0f), 1.0f);
        wp2 = fminf(fmaxf(wp2, 0.0f), 1.0f);
        float ssum = ((wp0 + wp1) + wp2) + EPSF;
        wp0 = wp0 / ssum; wp1 = wp1 / ssum; wp2 = wp2 / ssum;
        int t0 = min(max((int)floorf(wp0 * (float)TSZ), 0), TSZ - 1);
        int t1 = min(max((int)floorf(wp1 * (float)TSZ), 0), TSZ - 1);
        int t2 = min(max((int)floorf(wp2 * (float)TSZ), 0), TSZ - 1);
        const float* tp = tex + ((((((size_t)b * F + bestf) * TSZ + t0) * TSZ + t1) * TSZ + t2) * 3);
        o0 = tp[0] * blight;
        o1 = tp[1] * blight;
        o2 = tp[2] * blight;
    }

    int p = i * ISZ + j;
    out[((size_t)b * 3 + 0) * HW + p] = o0;
    out[((size_t)b * 3 + 1) * HW + p] = o1;
    out[((size_t)b * 3 + 2) * HW + p] = o2;
}

extern "C" void kernel_launch(void* const* d_in, const int* in_sizes, int n_in,
                              void* d_out, int out_size, void* d_ws, size_t ws_size,
                              hipStream_t stream) {
    const float* T     = (const float*)d_in[0];
    const float* verts = (const float*)d_in[1];
    const int*   faces = (const int*)d_in[2];
    const float* tex   = (const float*)d_in[3];
    const float* Km    = (const float*)d_in[4];
    const float* dist  = (const float*)d_in[5];

    int B = in_sizes[0] / 16;
    int V = in_sizes[1] / (3 * B);
    int F = in_sizes[2] / (3 * B);

    float* rec = (float*)d_ws;  // B*F*REC floats = 160 KB for B=2,F=1000

    int nfaces = B * F;
    face_pre<<<(nfaces + 255) / 256, 256, 0, stream>>>(T, verts, faces, Km, dist, rec, B, V, F);

    raster_tiled<<<B * NTILES, 64, 0, stream>>>(rec, tex, (float*)d_out, B, F);
}

// Round 8
// 57.714 us; speedup vs baseline: 6.1208x; 2.8871x over previous
//
#include <hip/hip_runtime.h>

#define ISZ 128
#define HW (ISZ * ISZ)
#define TSZ 4
#define NEARP 0.1f
#define FARP 100.0f
#define EPSF 1e-9f
#define TILE 8
#define NTJ (ISZ / TILE)     // 16 tiles per row
#define NTILES (NTJ * NTJ)   // 256 tiles per image
#define NW 8                 // waves per raster block

// d_ws layout: float4 bbox[B*F]  (umin,umax,vmin,vmax)  -- 32 KB
//              float4 data[B*F*4]                        -- 128 KB
// data record (4 float4s):
//   d0 = {c00, c01, c02, c10}
//   d1 = {c11, c12, c20, c21}
//   d2 = {c22, z0,  z1,  z2 }
//   d3 = {light, (face idx patched at staging), 0, 0}

__global__ void face_pre(const float* __restrict__ T,
                         const float* __restrict__ verts,
                         const int* __restrict__ faces,
                         const float* __restrict__ Km,
                         const float* __restrict__ dist,
                         float4* __restrict__ bbox,
                         float4* __restrict__ data,
                         int B, int V, int F) {
#pragma clang fp contract(off)
    int t = blockIdx.x * blockDim.x + threadIdx.x;
    if (t >= B * F) return;
    int b = t / F, f = t - b * F;

    const float* Tb = T + b * 16;
    const float* Kb = Km + b * 9;
    const float* Db = dist + b * 5;
    float k1 = Db[0], k2 = Db[1], p1 = Db[2], p2 = Db[3], k3 = Db[4];

    int idx0 = faces[((size_t)b * F + f) * 3 + 0];
    int idx1 = faces[((size_t)b * F + f) * 3 + 1];
    int idx2 = faces[((size_t)b * F + f) * 3 + 2];
    int idx[3] = {idx0, idx1, idx2};

    float P[3][3];
    for (int k = 0; k < 3; ++k) {
        const float* vp = verts + ((size_t)b * V + idx[k]) * 3;
        P[k][0] = vp[0]; P[k][1] = vp[1]; P[k][2] = vp[2];
    }

    // ---- lighting: n = cross(v12, v10), normalized; cos = relu(n_y) ----
    float v10x = P[0][0] - P[1][0], v10y = P[0][1] - P[1][1], v10z = P[0][2] - P[1][2];
    float v12x = P[2][0] - P[1][0], v12y = P[2][1] - P[1][1], v12z = P[2][2] - P[1][2];
    float nx = v12y * v10z - v12z * v10y;
    float ny = v12z * v10x - v12x * v10z;
    float nz = v12x * v10y - v12y * v10x;
    float norm = sqrtf((nx * nx + ny * ny) + nz * nz);
    float cosv = ny / (norm + EPSF);
    cosv = fmaxf(cosv, 0.0f);
    float light = 0.5f + 0.5f * cosv;

    // ---- project the 3 vertices (exact reference op order) ----
    float xs[3], ys[3], zs[3];
    for (int k = 0; k < 3; ++k) {
        float X = P[k][0], Y = P[k][1], Z = P[k][2];
        float vcx = ((Tb[0] * X + Tb[1] * Y) + Tb[2] * Z) + Tb[3];
        float vcy = ((Tb[4] * X + Tb[5] * Y) + Tb[6] * Z) + Tb[7];
        float vcz = ((Tb[8] * X + Tb[9] * Y) + Tb[10] * Z) + Tb[11];
        float zq = vcz + EPSF;
        float x_ = vcx / zq;
        float y_ = vcy / zq;
        float r2 = x_ * x_ + y_ * y_;
        float rad = ((1.0f + k1 * r2) + (k2 * r2) * r2) + ((k3 * r2) * r2) * r2;
        float xd = (x_ * rad + ((2.0f * p1) * x_) * y_) + p2 * (r2 + (2.0f * x_) * x_);
        float yd = (y_ * rad + p1 * (r2 + (2.0f * y_) * y_)) + ((2.0f * p2) * x_) * y_;
        float pixx = (Kb[0] * xd + Kb[1] * yd) + Kb[2];
        float pixy = (Kb[3] * xd + Kb[4] * yd) + Kb[5];
        float u = (2.0f * (pixx - (float)ISZ / 2.0f)) / (float)ISZ;
        float v = (2.0f * (((float)ISZ - pixy) - (float)ISZ / 2.0f)) / (float)ISZ;
        xs[k] = u; ys[k] = v; zs[k] = vcz;
    }

    float x0 = xs[0], x1 = xs[1], x2 = xs[2];
    float y0 = ys[0], y1 = ys[1], y2 = ys[2];

    float det = (x0 * (y1 - y2) + x1 * (y2 - y0)) + x2 * (y0 - y1);
    bool degen = fabsf(det) < 1e-6f;
    if (degen) det = 1e-6f;

    float c00 = (y1 - y2) / det, c01 = (x2 - x1) / det, c02 = (x1 * y2 - x2 * y1) / det;
    float c10 = (y2 - y0) / det, c11 = (x0 - x2) / det, c12 = (x2 * y0 - x0 * y2) / det;
    float c20 = (y0 - y1) / det, c21 = (x1 - x0) / det, c22 = (x0 * y1 - x1 * y0) / det;

    float umin, umax, vmin, vmax;
    if (degen) {
        // clamped-det faces rasterize as an unbounded thin band: disable culling.
        umin = -1e30f; umax = 1e30f; vmin = -1e30f; vmax = 1e30f;
    } else {
        umin = fminf(fminf(x0, x1), x2) - 1e-3f;
        umax = fmaxf(fmaxf(x0, x1), x2) + 1e-3f;
        vmin = fminf(fminf(y0, y1), y2) - 1e-3f;
        vmax = fmaxf(fmaxf(y0, y1), y2) + 1e-3f;
    }

    bbox[t] = make_float4(umin, umax, vmin, vmax);
    float4* dp = data + (size_t)t * 4;
    dp[0] = make_float4(c00, c01, c02, c10);
    dp[1] = make_float4(c11, c12, c20, c21);
    dp[2] = make_float4(c22, zs[0], zs[1], zs[2]);
    dp[3] = make_float4(light, 0.0f, 0.0f, 0.0f);
}

// 8 waves per 8x8-pixel tile. Waves split the FACE range (contiguous chunks,
// ascending index). Each wave: lane-parallel bbox cull -> ballot-compact into
// its own LDS candidate buffer -> all 64 pixels scan candidates (broadcast
// ds_read_b128). Final per-pixel reduction across the 8 waves picks min
// (zp, face idx) -- preserving argmin first-occurrence tie-break.
__global__ __launch_bounds__(NW * 64) void raster_tiled(
        const float4* __restrict__ bbox,
        const float4* __restrict__ data,
        const float* __restrict__ tex,
        float* __restrict__ out,
        int B, int F) {
#pragma clang fp contract(off)
    __shared__ float4 cand[NW][64 * 4];   // 32 KB: per-wave candidate buffers
    __shared__ float  red[9][NW][64];     // 18 KB: per-pixel partials

    int blk = blockIdx.x;
    int b = blk / NTILES, tile = blk - b * NTILES;
    int ti = tile / NTJ, tj = tile - ti * NTJ;
    int tid = threadIdx.x;
    int wid = tid >> 6, lane = tid & 63;
    int li = lane / TILE, lj = lane - li * TILE;
    int i = ti * TILE + li;
    int j = tj * TILE + lj;

    float px = (float)(2 * j + 1 - ISZ) / (float)ISZ;
    float py = (float)(2 * i + 1 - ISZ) / (float)ISZ;
    float pxmin = (float)(2 * (tj * TILE) + 1 - ISZ) / (float)ISZ;
    float pxmax = (float)(2 * (tj * TILE + TILE - 1) + 1 - ISZ) / (float)ISZ;
    float pymin = (float)(2 * (ti * TILE) + 1 - ISZ) / (float)ISZ;
    float pymax = (float)(2 * (ti * TILE + TILE - 1) + 1 - ISZ) / (float)ISZ;

    const float4* bb_b = bbox + (size_t)b * F;
    const float4* dt_b = data + (size_t)b * F * 4;

    int nch = (F + 63) >> 6;             // total 64-face chunks
    int cpw = (nch + NW - 1) / NW;       // chunks per wave (uniform loop bound)

    float best = FARP;
    int bestf = -1;
    float bw0 = 0, bw1 = 0, bw2 = 0, bz0 = 1, bz1 = 1, bz2 = 1, blight = 0;

    float4* cw = cand[wid];

    for (int it = 0; it < cpw; ++it) {
        int ci = wid * cpw + it;
        int f = (ci << 6) + lane;
        bool pass = false;
        if (ci < nch && f < F) {
            float4 r = bb_b[f];
            pass = (r.x <= pxmax) & (r.y >= pxmin) & (r.z <= pymax) & (r.w >= pymin);
        }
        unsigned long long m = __ballot(pass);
        int nc = __popcll(m);
        if (pass) {
            int slot = __popcll(m & ((1ull << lane) - 1ull));
            const float4* dp = dt_b + (size_t)f * 4;
            float4 d0 = dp[0], d1 = dp[1], d2 = dp[2], d3 = dp[3];
            d3.y = __int_as_float(f);
            cw[slot * 4 + 0] = d0;
            cw[slot * 4 + 1] = d1;
            cw[slot * 4 + 2] = d2;
            cw[slot * 4 + 3] = d3;
        }
        __syncthreads();  // uniform (cpw loop); makes wave's LDS writes visible

        for (int k = 0; k < nc; ++k) {
            float4 d0 = cw[k * 4 + 0];
            float4 d1 = cw[k * 4 + 1];
            float4 d2 = cw[k * 4 + 2];
            float4 d3 = cw[k * 4 + 3];
            float w0 = (d0.x * px + d0.y * py) + d0.z;
            float w1 = (d0.w * px + d1.x * py) + d1.y;
            float w2 = (d1.z * px + d1.w * py) + d2.x;
            bool inside = (w0 >= 0.0f) & (w0 <= 1.0f) &
                          (w1 >= 0.0f) & (w1 <= 1.0f) &
                          (w2 >= 0.0f) & (w2 <= 1.0f);
            float s = ((w0 / d2.y) + (w1 / d2.z)) + (w2 / d2.w);
            float zp = 1.0f / s;
            bool ok = inside & (zp > NEARP) & (zp < FARP) & (zp < best);
            if (ok) {
                best = zp; bestf = __float_as_int(d3.y);
                bw0 = w0; bw1 = w1; bw2 = w2;
                bz0 = d2.y; bz1 = d2.z; bz2 = d2.w;
                blight = d3.x;
            }
        }
        __syncthreads();
    }

    // ---- cross-wave per-pixel reduction ----
    red[0][wid][lane] = best;
    red[1][wid][lane] = __int_as_float(bestf);
    red[2][wid][lane] = bw0;
    red[3][wid][lane] = bw1;
    red[4][wid][lane] = bw2;
    red[5][wid][lane] = bz0;
    red[6][wid][lane] = bz1;
    red[7][wid][lane] = bz2;
    red[8][wid][lane] = blight;
    __syncthreads();

    if (wid == 0) {
        for (int w = 1; w < NW; ++w) {
            float zp = red[0][w][lane];
            int f = __float_as_int(red[1][w][lane]);
            // take if strictly nearer, or equal depth with lower face index.
            // unsigned compare: -1 -> 0xFFFFFFFF (never wins a tie vs real hit)
            bool take = (zp < best) ||
                        ((zp == best) && ((unsigned)f < (unsigned)bestf));
            if (take) {
                best = zp; bestf = f;
                bw0 = red[2][w][lane]; bw1 = red[3][w][lane]; bw2 = red[4][w][lane];
                bz0 = red[5][w][lane]; bz1 = red[6][w][lane]; bz2 = red[7][w][lane];
                blight = red[8][w][lane];
            }
        }

        float o0 = 0.0f, o1 = 0.0f, o2 = 0.0f;
        if (bestf >= 0) {
            float wp0 = (bw0 / bz0) * best;
            float wp1 = (bw1 / bz1) * best;
            float wp2 = (bw2 / bz2) * best;
            wp0 = fminf(fmaxf(wp0, 0.0f), 1.0f);
            wp1 = fminf(fmaxf(wp1, 0.0f), 1.0f);
            wp2 = fminf(fmaxf(wp2, 0.0f), 1.0f);
            float ssum = ((wp0 + wp1) + wp2) + EPSF;
            wp0 = wp0 / ssum; wp1 = wp1 / ssum; wp2 = wp2 / ssum;
            int t0 = min(max((int)floorf(wp0 * (float)TSZ), 0), TSZ - 1);
            int t1 = min(max((int)floorf(wp1 * (float)TSZ), 0), TSZ - 1);
            int t2 = min(max((int)floorf(wp2 * (float)TSZ), 0), TSZ - 1);
            const float* tp = tex + ((((((size_t)b * F + bestf) * TSZ + t0) * TSZ + t1) * TSZ + t2) * 3);
            o0 = tp[0] * blight;
            o1 = tp[1] * blight;
            o2 = tp[2] * blight;
        }

        int p = i * ISZ + j;
        out[((size_t)b * 3 + 0) * HW + p] = o0;
        out[((size_t)b * 3 + 1) * HW + p] = o1;
        out[((size_t)b * 3 + 2) * HW + p] = o2;
    }
}

extern "C" void kernel_launch(void* const* d_in, const int* in_sizes, int n_in,
                              void* d_out, int out_size, void* d_ws, size_t ws_size,
                              hipStream_t stream) {
    const float* T     = (const float*)d_in[0];
    const float* verts = (const float*)d_in[1];
    const int*   faces = (const int*)d_in[2];
    const float* tex   = (const float*)d_in[3];
    const float* Km    = (const float*)d_in[4];
    const float* dist  = (const float*)d_in[5];

    int B = in_sizes[0] / 16;
    int V = in_sizes[1] / (3 * B);
    int F = in_sizes[2] / (3 * B);

    float4* bbox = (float4*)d_ws;          // B*F float4s
    float4* data = bbox + (size_t)B * F;   // B*F*4 float4s (160 KB total)

    int nfaces = B * F;
    face_pre<<<(nfaces + 255) / 256, 256, 0, stream>>>(T, verts, faces, Km, dist,
                                                       bbox, data, B, V, F);

    raster_tiled<<<B * NTILES, NW * 64, 0, stream>>>(bbox, data, tex,
                                                     (float*)d_out, B, F);
}